// Round 8
// baseline (123.554 us; speedup 1.0000x reference)
//
#include <hip/hip_runtime.h>

typedef unsigned long long u64;
typedef unsigned int u32;
typedef _Float16 f16;

#define NN 50000
#define NE 600000
#define D  128
#define NWAVE 3125        // 50000 / 16 rows per GEMM wave
#define GGEMM 782         // ceil(3125 / 4 waves per block)
#define EPB 2048          // edges per partition-pass block (8 per thread)
#define NB_P 293          // ceil(600000 / 2048)
#define NP 196            // partitions: col >> 8 (256 nodes each)
#define NSTRIP 2          // hop strips: 64 fp16 cols = 128B = one full line
#define GS 1563           // hop blocks per strip: ceil(50000/32)

typedef __attribute__((ext_vector_type(8))) __bf16 bf16x8;
typedef __attribute__((ext_vector_type(8))) unsigned short us8;
typedef __attribute__((ext_vector_type(8))) f16 f16x8;
typedef __attribute__((ext_vector_type(4))) float f32x4;

__device__ __forceinline__ unsigned short f2bf(float f) {
    u32 u = __float_as_uint(f);
    return (unsigned short)((u + 0x7FFFu + ((u >> 16) & 1u)) >> 16);  // RNE
}
__device__ __forceinline__ float bf2f(unsigned short h) {
    return __uint_as_float((u32)h << 16);
}

// ---------------------------------------------------------------------------
// wprep: convert W ONCE into frag-order split-bf16 tables (2048 chunks).
// chunk i = kc4*512 + nt*64 + ln holds W[nt*16+(ln&15)][kc4*32+(ln>>4)*8+e].
// Removes the per-GEMM-block redundant conversion (~100k VALU ops x 782).
// ---------------------------------------------------------------------------
__global__ __launch_bounds__(256) void wprep(const float* __restrict__ W,
                                             us8* __restrict__ Whi,
                                             us8* __restrict__ Wlo) {
    const int i = blockIdx.x * 256 + threadIdx.x;
    if (i < 2048) {
        const int ln = i & 63, nt = (i >> 6) & 7, kc4 = i >> 9;
        const float* p =
            W + (size_t)(nt * 16 + (ln & 15)) * D + kc4 * 32 + (ln >> 4) * 8;
        float v[8];
        *(float4*)&v[0] = *(const float4*)p;
        *(float4*)&v[4] = *(const float4*)(p + 4);
        us8 hi, lo;
#pragma unroll
        for (int j = 0; j < 8; ++j) {
            const unsigned short hb = f2bf(v[j]);
            hi[j] = hb;
            lo[j] = f2bf(v[j] - bf2f(hb));
        }
        Whi[i] = hi;
        Wlo[i] = lo;
    }
}

// ---------------------------------------------------------------------------
// Fused kernel. Blocks [0, NB_P): partition COUNT — per-block 196-bin LDS
//   histogram of col>>8; writes cnt[p][b]. Block 0 zeroes the scan ticket.
// Blocks [NB_P, ...): GEMM h16 = fp16(x @ W^T), split-bf16 MFMA. Whi/Wlo
//   tables staged via plain b128 copies (no conversion). Epilogue bounces
//   through 16KB LDS (row-XOR swizzle) -> coalesced 16B f16x8 stores.
//   Output fp16 strip-major [2][NN][64].
// ---------------------------------------------------------------------------
__global__ __launch_bounds__(256) void gemm_count(
    const float* __restrict__ x, const us8* __restrict__ Whi,
    const us8* __restrict__ Wlo, f16* __restrict__ h16,
    const int* __restrict__ col, int* __restrict__ cnt,
    u32* __restrict__ done) {
    const int t = threadIdx.x;
    __shared__ us8 WH[2048];  // 32 KB hi; reused as bins (count) + epilogue
    __shared__ us8 WL[2048];  // 32 KB lo

    if (blockIdx.x < NB_P) {
        // ---- partition-count role ----
        if (blockIdx.x == 0 && t == 0) *done = 0u;  // ticket for scan_fused
        int* bins = (int*)WH;
        for (int i = t; i < NP; i += 256) bins[i] = 0;
        __syncthreads();
        const int e0 = blockIdx.x * EPB + t;
#pragma unroll
        for (int s = 0; s < 8; ++s) {
            const int e = e0 + s * 256;
            if (e < NE) atomicAdd(&bins[col[e] >> 8], 1);
        }
        __syncthreads();
        for (int i = t; i < NP; i += 256)
            cnt[i * NB_P + blockIdx.x] = bins[i];
        return;
    }

    // ---- GEMM role ----
    const int bg = blockIdx.x - NB_P;
    const int wv = t >> 6, lane = t & 63;
    const int g = bg * 4 + wv;
    const int gc = (g < NWAVE) ? g : (NWAVE - 1);  // dead waves: benign dup
    const int row0 = gc * 16;

    // issue all 8 cold x loads up front (128B/lane, 16 full lines per wave)
    const float* px = x + (size_t)(row0 + (lane & 15)) * D + (lane >> 4) * 8;
    float4 ar[8];
#pragma unroll
    for (int c = 0; c < 4; ++c) {
        ar[2 * c]     = *(const float4*)(px + c * 32);
        ar[2 * c + 1] = *(const float4*)(px + c * 32 + 4);
    }

    // stage pre-converted tables (64KB, plain b128 copies, L2-resident)
#pragma unroll
    for (int i = 0; i < 8; ++i) {
        WH[t + i * 256] = Whi[t + i * 256];
        WL[t + i * 256] = Wlo[t + i * 256];
    }
    __syncthreads();

    f32x4 acc[8];
#pragma unroll
    for (int nt = 0; nt < 8; ++nt) acc[nt] = (f32x4){0.f, 0.f, 0.f, 0.f};

#pragma unroll
    for (int c = 0; c < 4; ++c) {
        float v[8];
        *(float4*)&v[0] = ar[2 * c];
        *(float4*)&v[4] = ar[2 * c + 1];
        us8 hiu, lou;
#pragma unroll
        for (int j = 0; j < 8; ++j) {
            const unsigned short hb = f2bf(v[j]);
            hiu[j] = hb;
            lou[j] = f2bf(v[j] - bf2f(hb));
        }
        const bf16x8 ah = *(const bf16x8*)&hiu;
        const bf16x8 al = *(const bf16x8*)&lou;
#pragma unroll
        for (int nt = 0; nt < 8; ++nt) {
            const bf16x8 bh = *(const bf16x8*)&WH[c * 512 + nt * 64 + lane];
            const bf16x8 bl = *(const bf16x8*)&WL[c * 512 + nt * 64 + lane];
            acc[nt] = __builtin_amdgcn_mfma_f32_16x16x32_bf16(ah, bh, acc[nt], 0, 0, 0);
            acc[nt] = __builtin_amdgcn_mfma_f32_16x16x32_bf16(al, bh, acc[nt], 0, 0, 0);
            acc[nt] = __builtin_amdgcn_mfma_f32_16x16x32_bf16(ah, bl, acc[nt], 0, 0, 0);
        }
    }

    // epilogue: C/D layout col = lane&15, row = (lane>>4)*4 + r (verified).
    // Bounce through LDS [2][64][64] f16 (col8 XOR row&7 swizzle) so the
    // global stores are coalesced 16B f16x8 instead of 32 scattered 2B.
    __syncthreads();  // all WH/WL reads complete before overwrite
    f16* eb = (f16*)WH;
    const int q = lane >> 4, cl = lane & 15;
#pragma unroll
    for (int nt = 0; nt < 8; ++nt) {
        const int s = nt >> 2;
        const int lcol = (nt & 3) * 16 + cl;
        const int c8 = lcol >> 3, ci = lcol & 7;
#pragma unroll
        for (int r = 0; r < 4; ++r) {
            const int lrow = wv * 16 + q * 4 + r;
            eb[s * 4096 + lrow * 64 + ((c8 ^ (lrow & 7)) << 3) + ci] =
                (f16)acc[nt][r];
        }
    }
    __syncthreads();
    const int B0 = bg * 64;
#pragma unroll
    for (int i = 0; i < 4; ++i) {
        const int idx = i * 256 + t;               // 0..1023
        const int c8 = idx & 7;
        const int lrow = (idx >> 3) & 63;
        const int s = idx >> 9;
        const int grow = B0 + lrow;
        if (grow < NN) {
            const f16x8 v =
                *(const f16x8*)&eb[s * 4096 + lrow * 64 + ((c8 ^ (lrow & 7)) << 3)];
            *(f16x8*)(h16 + (size_t)s * ((size_t)NN * 64) + (size_t)grow * 64 +
                      c8 * 8) = v;
        }
    }
}

// ---------------------------------------------------------------------------
// scan_fused: per-partition exclusive scan over NB_P block-counts (in place)
// + last-block-done partition-totals scan. Cross-XCD safety: totals published
// via device-scope atomicExch; last block reads back via atomic add-0.
__global__ __launch_bounds__(256) void scan_fused(
    int* __restrict__ cnt, int* __restrict__ totals,
    int* __restrict__ binbase, int* __restrict__ base,
    u32* __restrict__ done) {
    __shared__ int sw[256];
    __shared__ u32 ticket;
    const int p = blockIdx.x, tid = threadIdx.x;
    const int i0 = 2 * tid, i1 = 2 * tid + 1;
    const int a0 = (i0 < NB_P) ? cnt[p * NB_P + i0] : 0;
    const int a1 = (i1 < NB_P) ? cnt[p * NB_P + i1] : 0;
    const int pair = a0 + a1;
    sw[tid] = pair;
    __syncthreads();
    for (int off = 1; off < 256; off <<= 1) {
        int tv = (tid >= off) ? sw[tid - off] : 0;
        __syncthreads();
        if (tid >= off) sw[tid] += tv;
        __syncthreads();
    }
    const int excl = sw[tid] - pair;
    if (i0 < NB_P) cnt[p * NB_P + i0] = excl;
    if (i1 < NB_P) cnt[p * NB_P + i1] = excl + a0;
    if (tid == 0) {
        atomicExch(&totals[p], sw[255]);  // device-scope publish
        __threadfence();
        ticket = atomicAdd(done, 1u);
    }
    __syncthreads();
    if (ticket != NP - 1) return;

    const int v = (tid < NP) ? atomicAdd(&totals[tid], 0) : 0;
    sw[tid] = v;
    __syncthreads();
    for (int off = 1; off < 256; off <<= 1) {
        int tv = (tid >= off) ? sw[tid - off] : 0;
        __syncthreads();
        if (tid >= off) sw[tid] += tv;
        __syncthreads();
    }
    if (tid < NP) binbase[tid] = sw[tid] - v;
    if (tid == NP - 1) {
        binbase[NP] = sw[tid];  // == NE
        base[NN] = sw[tid];
    }
}

// ---------------------------------------------------------------------------
// scatter edges into partition-contiguous part[] (u64: w|row|colloc).
__global__ __launch_bounds__(256) void scatter_k(
    const int* __restrict__ row, const int* __restrict__ col,
    const float* __restrict__ w, const int* __restrict__ cnt,
    const int* __restrict__ binbase, u64* __restrict__ part) {
    __shared__ int bins[NP];
    __shared__ int off0[NP];
    const int b = blockIdx.x, t = threadIdx.x;
    for (int i = t; i < NP; i += 256) {
        bins[i] = 0;
        off0[i] = binbase[i] + cnt[i * NB_P + b];
    }
    __syncthreads();
    const int e0 = b * EPB + t;
#pragma unroll
    for (int s = 0; s < 8; ++s) {
        const int e = e0 + s * 256;
        if (e < NE) {
            const int c = col[e];
            const int p = c >> 8;
            const int lr = atomicAdd(&bins[p], 1);
            part[off0[p] + lr] = ((u64)__float_as_uint(w[e]) << 32) |
                                 ((u32)row[e] << 8) | (u32)(c & 255);
        }
    }
}

// ---------------------------------------------------------------------------
// per-partition CSR finish: count + weighted degree -> dinv; scan ->
// base[node]; scatter sedge with PARTIAL norm w*dinv[col] (dinv[row] is
// applied inside the hops).
__global__ __launch_bounds__(256) void csr_k(
    const u64* __restrict__ part, const int* __restrict__ binbase,
    int* __restrict__ base, float* __restrict__ dinv,
    int2* __restrict__ sedge) {
    __shared__ u32 cntL[256];
    __shared__ float wsL[256];   // weighted degree, then reused as dinv
    __shared__ int curL[256];
    __shared__ int sw[256];
    const int p = blockIdx.x, tid = threadIdx.x;
    const int eb = binbase[p], ee = binbase[p + 1];

    cntL[tid] = 0u;
    wsL[tid] = 0.f;
    __syncthreads();
    for (int e = eb + tid; e < ee; e += 256) {
        const u64 pk = part[e];
        const int cl = (int)(pk & 255u);
        atomicAdd(&cntL[cl], 1u);
        atomicAdd(&wsL[cl], __uint_as_float((u32)(pk >> 32)));
    }
    __syncthreads();

    const int node = p * 256 + tid;
    const float di = rsqrtf(1.0f + wsL[tid]);  // deg = 1 (self) + sum_in w
    const int myc = (int)cntL[tid];
    sw[tid] = myc;
    __syncthreads();
    for (int off = 1; off < 256; off <<= 1) {
        int tv = (tid >= off) ? sw[tid - off] : 0;
        __syncthreads();
        if (tid >= off) sw[tid] += tv;
        __syncthreads();
    }
    const int excl = sw[tid] - myc;
    if (node < NN) {
        dinv[node] = di;
        base[node] = eb + excl;
    }
    __syncthreads();
    wsL[tid] = di;
    curL[tid] = excl;
    __syncthreads();

    for (int e = eb + tid; e < ee; e += 256) {
        const u64 pk = part[e];
        const int cl = (int)(pk & 255u);
        const int r = (int)((pk >> 8) & 0xFFFFu);
        const float wv = __uint_as_float((u32)(pk >> 32));
        const int lr = atomicAdd(&curL[cl], 1);
        int2 ed;
        ed.x = r;
        ed.y = __float_as_int(wv * wsL[cl]);  // partial norm: w * dinv[col]
        sedge[eb + lr] = ed;
    }
}

// ---------------------------------------------------------------------------
// one hop: dst[n] = dinv[n]^2 * src[n] + sum_in (w*dinv[r]*dinv[n]) * src[r]
// sedge.y = w*dinv[col]; dinv[row] applied in-loop (L2-resident table).
// fp16 strip-major [2][NN][64]: each gather = exactly one 128B line (the
// measured-optimal granularity). 8-lane groups (fp16x8); blockIdx.y = strip.
// unroll 8: deeper MLP on the independent sedge+gather streams.
// OUTF=0: write fp16 strip-major; OUTF=1: write fp32 out.
// ---------------------------------------------------------------------------
template <int OUTF>
__global__ __launch_bounds__(256) void hop_kernel(
    const f16* __restrict__ src, f16* __restrict__ dst16,
    float* __restrict__ dstf, const int2* __restrict__ sedge,
    const int* __restrict__ base, const float* __restrict__ dinv) {
    const int node = blockIdx.x * 32 + (threadIdx.x >> 3);
    if (node >= NN) return;
    const int strip = blockIdx.y;
    const int lo8 = (threadIdx.x & 7) * 8;
    const f16* hs = src + (size_t)strip * ((size_t)NN * 64) + lo8;

    const int b = base[node];
    const int k = base[node + 1] - b;

    float acc[8] = {0.f, 0.f, 0.f, 0.f, 0.f, 0.f, 0.f, 0.f};
#pragma unroll 8
    for (int j = 0; j < k; ++j) {
        const int2 ed = sedge[b + j];
        const f16x8 hv = *(const f16x8*)(hs + (size_t)ed.x * 64);
        const float nm = __int_as_float(ed.y) * dinv[ed.x];
#pragma unroll
        for (int i = 0; i < 8; ++i) acc[i] = fmaf(nm, (float)hv[i], acc[i]);
    }
    const float di = dinv[node];
    const float d2 = di * di;
    const f16x8 sv = *(const f16x8*)(hs + (size_t)node * 64);
#pragma unroll
    for (int i = 0; i < 8; ++i) acc[i] = fmaf(d2, (float)sv[i], acc[i]);

    if (OUTF) {
        float* o = dstf + (size_t)node * D + strip * 64 + lo8;
        *(float4*)&o[0] = make_float4(acc[0], acc[1], acc[2], acc[3]);
        *(float4*)&o[4] = make_float4(acc[4], acc[5], acc[6], acc[7]);
    } else {
        f16x8 ov;
#pragma unroll
        for (int i = 0; i < 8; ++i) ov[i] = (f16)acc[i];
        *(f16x8*)(dst16 + (size_t)strip * ((size_t)NN * 64) + (size_t)node * 64 + lo8) = ov;
    }
}

// ---------------------------------------------------------------------------
extern "C" void kernel_launch(void* const* d_in, const int* in_sizes, int n_in,
                              void* d_out, int out_size, void* d_ws,
                              size_t ws_size, hipStream_t stream) {
    const float* x  = (const float*)d_in[0];
    const int*   ei = (const int*)d_in[1];  // [2, NE]: row then col
    const float* w  = (const float*)d_in[2];
    const float* W  = (const float*)d_in[3];
    float* out = (float*)d_out;

    const int* row = ei;
    const int* col = ei + NE;

    // workspace carve-up (~31 MB)
    f16* h16a = (f16*)d_ws;                          // 2*NN*64 f16 = 12.8MB
    f16* h16b = h16a + (size_t)2 * NN * 64;          // 12.8MB
    u64* part = (u64*)h16b;                          // 4.8MB alias (dead before hop1)
    int* cnt = (int*)(h16b + (size_t)2 * NN * 64);   // NP*NB_P ints (230KB)
    int* totals = cnt + NP * NB_P;                   // NP
    u32* done = (u32*)(totals + NP);                 // 1
    int* binbase = (int*)(done + 1);                 // NP+1
    int* base = binbase + NP + 1;                    // NN+1
    float* dinv = (float*)(base + NN + 1);           // NN
    int2* sedge = (int2*)(dinv + NN);                // NE int2 = 4.8MB
    us8* Whi = (us8*)(sedge + NE);                   // 32KB
    us8* Wlo = Whi + 2048;                           // 32KB

    wprep<<<8, 256, 0, stream>>>(W, Whi, Wlo);
    gemm_count<<<NB_P + GGEMM, 256, 0, stream>>>(x, Whi, Wlo, h16a, col, cnt, done);
    scan_fused<<<NP, 256, 0, stream>>>(cnt, totals, binbase, base, done);
    scatter_k<<<NB_P, 256, 0, stream>>>(row, col, w, cnt, binbase, part);
    csr_k<<<NP, 256, 0, stream>>>(part, binbase, base, dinv, sedge);

    hop_kernel<0><<<dim3(GS, NSTRIP), 256, 0, stream>>>(h16a, h16b, nullptr,
                                                        sedge, base, dinv);
    hop_kernel<1><<<dim3(GS, NSTRIP), 256, 0, stream>>>(h16b, nullptr, out,
                                                        sedge, base, dinv);
}

// Round 9
// 106.437 us; speedup vs baseline: 1.1608x; 1.1608x over previous
//
#include <hip/hip_runtime.h>

typedef unsigned long long u64;
typedef unsigned int u32;
typedef _Float16 f16;

#define NN 50000
#define NE 600000
#define D  128
#define NWAVE 3125        // 50000 / 16 rows per GEMM wave
#define GGEMM 782         // ceil(3125 / 4 waves per block)
#define EPB 2048          // edges per partition-pass block (8 per thread)
#define NB_P 293          // ceil(600000 / 2048)
#define NP 196            // partitions: col >> 8 (256 nodes each)
#define NSTRIP 2          // hop strips: 64 fp16 cols = 128B = one full line
#define GS 1563           // hop blocks per strip: ceil(50000/32)

typedef __attribute__((ext_vector_type(8))) __bf16 bf16x8;
typedef __attribute__((ext_vector_type(8))) unsigned short us8;
typedef __attribute__((ext_vector_type(8))) f16 f16x8;
typedef __attribute__((ext_vector_type(4))) float f32x4;

__device__ __forceinline__ unsigned short f2bf(float f) {
    u32 u = __float_as_uint(f);
    return (unsigned short)((u + 0x7FFFu + ((u >> 16) & 1u)) >> 16);  // RNE
}
__device__ __forceinline__ float bf2f(unsigned short h) {
    return __uint_as_float((u32)h << 16);
}

// ---------------------------------------------------------------------------
// wprep: convert W ONCE into frag-order split-bf16 tables (2048 chunks).
// chunk i = kc4*512 + nt*64 + ln holds W[nt*16+(ln&15)][kc4*32+(ln>>4)*8+e].
// Deletes the per-GEMM-block redundant conversion (~500 VALU ops/thread).
// ---------------------------------------------------------------------------
__global__ __launch_bounds__(256) void wprep(const float* __restrict__ W,
                                             us8* __restrict__ Whi,
                                             us8* __restrict__ Wlo) {
    const int i = blockIdx.x * 256 + threadIdx.x;
    if (i < 2048) {
        const int ln = i & 63, nt = (i >> 6) & 7, kc4 = i >> 9;
        const float* p =
            W + (size_t)(nt * 16 + (ln & 15)) * D + kc4 * 32 + (ln >> 4) * 8;
        float v[8];
        *(float4*)&v[0] = *(const float4*)p;
        *(float4*)&v[4] = *(const float4*)(p + 4);
        us8 hi, lo;
#pragma unroll
        for (int j = 0; j < 8; ++j) {
            const unsigned short hb = f2bf(v[j]);
            hi[j] = hb;
            lo[j] = f2bf(v[j] - bf2f(hb));
        }
        Whi[i] = hi;
        Wlo[i] = lo;
    }
}

// ---------------------------------------------------------------------------
// Fused kernel. Blocks [0, NB_P): partition COUNT — per-block 196-bin LDS
//   histogram of col>>8; writes cnt[p][b]. Block 0 zeroes the scan ticket.
// Blocks [NB_P, ...): GEMM h16 = fp16(x @ W^T), split-bf16 MFMA. Whi/Wlo
//   tables staged via plain b128 copies (no per-block conversion).
//   Output fp16 strip-major [2][NN][64], direct scattered stores (the
//   round-8 LDS-bounce epilogue + its 2 barriers regressed; reverted).
// ---------------------------------------------------------------------------
__global__ __launch_bounds__(256) void gemm_count(
    const float* __restrict__ x, const us8* __restrict__ Whi,
    const us8* __restrict__ Wlo, f16* __restrict__ h16,
    const int* __restrict__ col, int* __restrict__ cnt,
    u32* __restrict__ done) {
    const int t = threadIdx.x;
    __shared__ us8 WH[2048];  // 32 KB hi; reused as bins (count role)
    __shared__ us8 WL[2048];  // 32 KB lo

    if (blockIdx.x < NB_P) {
        // ---- partition-count role ----
        if (blockIdx.x == 0 && t == 0) *done = 0u;  // ticket for scan_fused
        int* bins = (int*)WH;
        for (int i = t; i < NP; i += 256) bins[i] = 0;
        __syncthreads();
        const int e0 = blockIdx.x * EPB + t;
#pragma unroll
        for (int s = 0; s < 8; ++s) {
            const int e = e0 + s * 256;
            if (e < NE) atomicAdd(&bins[col[e] >> 8], 1);
        }
        __syncthreads();
        for (int i = t; i < NP; i += 256)
            cnt[i * NB_P + blockIdx.x] = bins[i];
        return;
    }

    // ---- GEMM role ----
    const int g = (blockIdx.x - NB_P) * 4 + (t >> 6);
    const int lane = t & 63;
    const int gc = (g < NWAVE) ? g : (NWAVE - 1);
    const int row0 = gc * 16;

    // issue all 8 cold x loads up front (128B/lane, 16 full lines per wave)
    const float* px = x + (size_t)(row0 + (lane & 15)) * D + (lane >> 4) * 8;
    float4 ar[8];
#pragma unroll
    for (int c = 0; c < 4; ++c) {
        ar[2 * c]     = *(const float4*)(px + c * 32);
        ar[2 * c + 1] = *(const float4*)(px + c * 32 + 4);
    }

    // stage pre-converted tables (64KB, plain b128 copies, L2-resident)
    // while the x loads are in flight
#pragma unroll
    for (int i = 0; i < 8; ++i) {
        WH[t + i * 256] = Whi[t + i * 256];
        WL[t + i * 256] = Wlo[t + i * 256];
    }
    __syncthreads();
    if (g >= NWAVE) return;

    f32x4 acc[8];
#pragma unroll
    for (int nt = 0; nt < 8; ++nt) acc[nt] = (f32x4){0.f, 0.f, 0.f, 0.f};

#pragma unroll
    for (int c = 0; c < 4; ++c) {
        float v[8];
        *(float4*)&v[0] = ar[2 * c];
        *(float4*)&v[4] = ar[2 * c + 1];
        us8 hiu, lou;
#pragma unroll
        for (int j = 0; j < 8; ++j) {
            const unsigned short hb = f2bf(v[j]);
            hiu[j] = hb;
            lou[j] = f2bf(v[j] - bf2f(hb));
        }
        const bf16x8 ah = *(const bf16x8*)&hiu;
        const bf16x8 al = *(const bf16x8*)&lou;
#pragma unroll
        for (int nt = 0; nt < 8; ++nt) {
            const bf16x8 bh = *(const bf16x8*)&WH[c * 512 + nt * 64 + lane];
            const bf16x8 bl = *(const bf16x8*)&WL[c * 512 + nt * 64 + lane];
            acc[nt] = __builtin_amdgcn_mfma_f32_16x16x32_bf16(ah, bh, acc[nt], 0, 0, 0);
            acc[nt] = __builtin_amdgcn_mfma_f32_16x16x32_bf16(al, bh, acc[nt], 0, 0, 0);
            acc[nt] = __builtin_amdgcn_mfma_f32_16x16x32_bf16(ah, bl, acc[nt], 0, 0, 0);
        }
    }

    // epilogue: C/D layout col = lane&15, row = (lane>>4)*4 + r (verified).
    // fp16 strip-major [2][NN][64]: strip = nt>>2, col = (nt&3)*16 + cl.
    const int q = lane >> 4, cl = lane & 15;
#pragma unroll
    for (int nt = 0; nt < 8; ++nt) {
        f16* o = h16 + (size_t)(nt >> 2) * ((size_t)NN * 64) + (nt & 3) * 16 + cl;
#pragma unroll
        for (int r = 0; r < 4; ++r)
            o[(size_t)(row0 + q * 4 + r) * 64] = (f16)acc[nt][r];
    }
}

// ---------------------------------------------------------------------------
// scan_fused: per-partition exclusive scan over NB_P block-counts (in place)
// + last-block-done partition-totals scan. Cross-XCD safety: totals published
// via device-scope atomicExch; last block reads back via atomic add-0.
__global__ __launch_bounds__(256) void scan_fused(
    int* __restrict__ cnt, int* __restrict__ totals,
    int* __restrict__ binbase, int* __restrict__ base,
    u32* __restrict__ done) {
    __shared__ int sw[256];
    __shared__ u32 ticket;
    const int p = blockIdx.x, tid = threadIdx.x;
    const int i0 = 2 * tid, i1 = 2 * tid + 1;
    const int a0 = (i0 < NB_P) ? cnt[p * NB_P + i0] : 0;
    const int a1 = (i1 < NB_P) ? cnt[p * NB_P + i1] : 0;
    const int pair = a0 + a1;
    sw[tid] = pair;
    __syncthreads();
    for (int off = 1; off < 256; off <<= 1) {
        int tv = (tid >= off) ? sw[tid - off] : 0;
        __syncthreads();
        if (tid >= off) sw[tid] += tv;
        __syncthreads();
    }
    const int excl = sw[tid] - pair;
    if (i0 < NB_P) cnt[p * NB_P + i0] = excl;
    if (i1 < NB_P) cnt[p * NB_P + i1] = excl + a0;
    if (tid == 0) {
        atomicExch(&totals[p], sw[255]);  // device-scope publish
        __threadfence();
        ticket = atomicAdd(done, 1u);
    }
    __syncthreads();
    if (ticket != NP - 1) return;

    const int v = (tid < NP) ? atomicAdd(&totals[tid], 0) : 0;
    sw[tid] = v;
    __syncthreads();
    for (int off = 1; off < 256; off <<= 1) {
        int tv = (tid >= off) ? sw[tid - off] : 0;
        __syncthreads();
        if (tid >= off) sw[tid] += tv;
        __syncthreads();
    }
    if (tid < NP) binbase[tid] = sw[tid] - v;
    if (tid == NP - 1) {
        binbase[NP] = sw[tid];  // == NE
        base[NN] = sw[tid];
    }
}

// ---------------------------------------------------------------------------
// scatter edges into partition-contiguous part[] (u64: w|row|colloc).
__global__ __launch_bounds__(256) void scatter_k(
    const int* __restrict__ row, const int* __restrict__ col,
    const float* __restrict__ w, const int* __restrict__ cnt,
    const int* __restrict__ binbase, u64* __restrict__ part) {
    __shared__ int bins[NP];
    __shared__ int off0[NP];
    const int b = blockIdx.x, t = threadIdx.x;
    for (int i = t; i < NP; i += 256) {
        bins[i] = 0;
        off0[i] = binbase[i] + cnt[i * NB_P + b];
    }
    __syncthreads();
    const int e0 = b * EPB + t;
#pragma unroll
    for (int s = 0; s < 8; ++s) {
        const int e = e0 + s * 256;
        if (e < NE) {
            const int c = col[e];
            const int p = c >> 8;
            const int lr = atomicAdd(&bins[p], 1);
            part[off0[p] + lr] = ((u64)__float_as_uint(w[e]) << 32) |
                                 ((u32)row[e] << 8) | (u32)(c & 255);
        }
    }
}

// ---------------------------------------------------------------------------
// per-partition CSR finish: count + weighted degree -> dinv; scan ->
// base[node]; scatter sedge with PARTIAL norm w*dinv[col] (dinv[row] is
// applied inside the hops).
__global__ __launch_bounds__(256) void csr_k(
    const u64* __restrict__ part, const int* __restrict__ binbase,
    int* __restrict__ base, float* __restrict__ dinv,
    int2* __restrict__ sedge) {
    __shared__ u32 cntL[256];
    __shared__ float wsL[256];   // weighted degree, then reused as dinv
    __shared__ int curL[256];
    __shared__ int sw[256];
    const int p = blockIdx.x, tid = threadIdx.x;
    const int eb = binbase[p], ee = binbase[p + 1];

    cntL[tid] = 0u;
    wsL[tid] = 0.f;
    __syncthreads();
    for (int e = eb + tid; e < ee; e += 256) {
        const u64 pk = part[e];
        const int cl = (int)(pk & 255u);
        atomicAdd(&cntL[cl], 1u);
        atomicAdd(&wsL[cl], __uint_as_float((u32)(pk >> 32)));
    }
    __syncthreads();

    const int node = p * 256 + tid;
    const float di = rsqrtf(1.0f + wsL[tid]);  // deg = 1 (self) + sum_in w
    const int myc = (int)cntL[tid];
    sw[tid] = myc;
    __syncthreads();
    for (int off = 1; off < 256; off <<= 1) {
        int tv = (tid >= off) ? sw[tid - off] : 0;
        __syncthreads();
        if (tid >= off) sw[tid] += tv;
        __syncthreads();
    }
    const int excl = sw[tid] - myc;
    if (node < NN) {
        dinv[node] = di;
        base[node] = eb + excl;
    }
    __syncthreads();
    wsL[tid] = di;
    curL[tid] = excl;
    __syncthreads();

    for (int e = eb + tid; e < ee; e += 256) {
        const u64 pk = part[e];
        const int cl = (int)(pk & 255u);
        const int r = (int)((pk >> 8) & 0xFFFFu);
        const float wv = __uint_as_float((u32)(pk >> 32));
        const int lr = atomicAdd(&curL[cl], 1);
        int2 ed;
        ed.x = r;
        ed.y = __float_as_int(wv * wsL[cl]);  // partial norm: w * dinv[col]
        sedge[eb + lr] = ed;
    }
}

// ---------------------------------------------------------------------------
// one hop: dst[n] = dinv[n]^2 * src[n] + sum_in (w*dinv[r]*dinv[n]) * src[r]
// sedge.y = w*dinv[col]; dinv[row] applied in-loop (L2-resident table).
// fp16 strip-major [2][NN][64]: each gather = exactly one 128B line.
// 8-lane groups (fp16x8); blockIdx.y = strip. unroll 4 (unroll 8 ballooned
// VGPRs past the 64-reg occupancy cliff and regressed 17 µs in round 8 —
// the hop lives on wave-count to hide miss latency).
// OUTF=0: write fp16 strip-major; OUTF=1: write fp32 out.
// ---------------------------------------------------------------------------
template <int OUTF>
__global__ __launch_bounds__(256) void hop_kernel(
    const f16* __restrict__ src, f16* __restrict__ dst16,
    float* __restrict__ dstf, const int2* __restrict__ sedge,
    const int* __restrict__ base, const float* __restrict__ dinv) {
    const int node = blockIdx.x * 32 + (threadIdx.x >> 3);
    if (node >= NN) return;
    const int strip = blockIdx.y;
    const int lo8 = (threadIdx.x & 7) * 8;
    const f16* hs = src + (size_t)strip * ((size_t)NN * 64) + lo8;

    const int b = base[node];
    const int k = base[node + 1] - b;

    float acc[8] = {0.f, 0.f, 0.f, 0.f, 0.f, 0.f, 0.f, 0.f};
#pragma unroll 4
    for (int j = 0; j < k; ++j) {
        const int2 ed = sedge[b + j];
        const f16x8 hv = *(const f16x8*)(hs + (size_t)ed.x * 64);
        const float nm = __int_as_float(ed.y) * dinv[ed.x];
#pragma unroll
        for (int i = 0; i < 8; ++i) acc[i] = fmaf(nm, (float)hv[i], acc[i]);
    }
    const float di = dinv[node];
    const float d2 = di * di;
    const f16x8 sv = *(const f16x8*)(hs + (size_t)node * 64);
#pragma unroll
    for (int i = 0; i < 8; ++i) acc[i] = fmaf(d2, (float)sv[i], acc[i]);

    if (OUTF) {
        float* o = dstf + (size_t)node * D + strip * 64 + lo8;
        *(float4*)&o[0] = make_float4(acc[0], acc[1], acc[2], acc[3]);
        *(float4*)&o[4] = make_float4(acc[4], acc[5], acc[6], acc[7]);
    } else {
        f16x8 ov;
#pragma unroll
        for (int i = 0; i < 8; ++i) ov[i] = (f16)acc[i];
        *(f16x8*)(dst16 + (size_t)strip * ((size_t)NN * 64) + (size_t)node * 64 + lo8) = ov;
    }
}

// ---------------------------------------------------------------------------
extern "C" void kernel_launch(void* const* d_in, const int* in_sizes, int n_in,
                              void* d_out, int out_size, void* d_ws,
                              size_t ws_size, hipStream_t stream) {
    const float* x  = (const float*)d_in[0];
    const int*   ei = (const int*)d_in[1];  // [2, NE]: row then col
    const float* w  = (const float*)d_in[2];
    const float* W  = (const float*)d_in[3];
    float* out = (float*)d_out;

    const int* row = ei;
    const int* col = ei + NE;

    // workspace carve-up (~31 MB)
    f16* h16a = (f16*)d_ws;                          // 2*NN*64 f16 = 12.8MB
    f16* h16b = h16a + (size_t)2 * NN * 64;          // 12.8MB
    u64* part = (u64*)h16b;                          // 4.8MB alias (dead before hop1)
    int* cnt = (int*)(h16b + (size_t)2 * NN * 64);   // NP*NB_P ints (230KB)
    int* totals = cnt + NP * NB_P;                   // NP
    u32* done = (u32*)(totals + NP);                 // 1
    int* binbase = (int*)(done + 1);                 // NP+1
    int* base = binbase + NP + 1;                    // NN+1
    float* dinv = (float*)(base + NN + 1);           // NN
    int2* sedge = (int2*)(dinv + NN);                // NE int2 = 4.8MB
    us8* Whi = (us8*)(sedge + NE);                   // 32KB
    us8* Wlo = Whi + 2048;                           // 32KB

    wprep<<<8, 256, 0, stream>>>(W, Whi, Wlo);
    gemm_count<<<NB_P + GGEMM, 256, 0, stream>>>(x, Whi, Wlo, h16a, col, cnt, done);
    scan_fused<<<NP, 256, 0, stream>>>(cnt, totals, binbase, base, done);
    scatter_k<<<NB_P, 256, 0, stream>>>(row, col, w, cnt, binbase, part);
    csr_k<<<NP, 256, 0, stream>>>(part, binbase, base, dinv, sedge);

    hop_kernel<0><<<dim3(GS, NSTRIP), 256, 0, stream>>>(h16a, h16b, nullptr,
                                                        sedge, base, dinv);
    hop_kernel<1><<<dim3(GS, NSTRIP), 256, 0, stream>>>(h16b, nullptr, out,
                                                        sedge, base, dinv);
}

// Round 10
// 94.369 us; speedup vs baseline: 1.3093x; 1.1279x over previous
//
#include <hip/hip_runtime.h>

typedef unsigned long long u64;
typedef unsigned int u32;
typedef _Float16 f16;

#define NN 50000
#define NE 600000
#define D  128
#define NWAVE 3125        // 50000 / 16 rows per GEMM wave
#define GGEMM 782         // ceil(3125 / 4 waves per block)
#define EPB 2048          // edges per scatter block (8 per thread)
#define NB_P 293          // ceil(600000 / 2048)
#define NP 196            // partitions: col >> 8 (256 nodes each)
#define MAXCAP 3584       // slab capacity/partition (mean 3061, sigma 55: 9.5σ)
#define NSTRIP 2          // hop strips: 64 fp16 cols = 128B = one full line
#define GS 1563           // hop blocks per strip: ceil(50000/32)

typedef __attribute__((ext_vector_type(8))) __bf16 bf16x8;
typedef __attribute__((ext_vector_type(8))) unsigned short us8;
typedef __attribute__((ext_vector_type(8))) f16 f16x8;
typedef __attribute__((ext_vector_type(4))) float f32x4;

__device__ __forceinline__ unsigned short f2bf(float f) {
    u32 u = __float_as_uint(f);
    return (unsigned short)((u + 0x7FFFu + ((u >> 16) & 1u)) >> 16);  // RNE
}
__device__ __forceinline__ float bf2f(unsigned short h) {
    return __uint_as_float((u32)h << 16);
}

// ---------------------------------------------------------------------------
// wprep: convert W ONCE into frag-order split-bf16 tables (2048 chunks) AND
// init the 196 partition slab cursors (pcur[p] = p*MAXCAP).
// ---------------------------------------------------------------------------
__global__ __launch_bounds__(256) void wprep(const float* __restrict__ W,
                                             us8* __restrict__ Whi,
                                             us8* __restrict__ Wlo,
                                             int* __restrict__ pcur) {
    const int i = blockIdx.x * 256 + threadIdx.x;
    if (i < NP) pcur[i] = i * MAXCAP;
    if (i < 2048) {
        const int ln = i & 63, nt = (i >> 6) & 7, kc4 = i >> 9;
        const float* p =
            W + (size_t)(nt * 16 + (ln & 15)) * D + kc4 * 32 + (ln >> 4) * 8;
        float v[8];
        *(float4*)&v[0] = *(const float4*)p;
        *(float4*)&v[4] = *(const float4*)(p + 4);
        us8 hi, lo;
#pragma unroll
        for (int j = 0; j < 8; ++j) {
            const unsigned short hb = f2bf(v[j]);
            hi[j] = hb;
            lo[j] = f2bf(v[j] - bf2f(hb));
        }
        Whi[i] = hi;
        Wlo[i] = lo;
    }
}

// ---------------------------------------------------------------------------
// Fused kernel. Blocks [0, NB_P): SCATTER — LDS-count the block's 2048 edges
//   by partition (cols cached in registers), reserve slab space with ONE
//   device atomicAdd per touched partition (57k total — 10x below the
//   600k-atomic wall measured in rounds 0-4), then write packed edges
//   (w|row|colloc u64) into the partition slab. Replaces the old
//   count -> scan_fused -> scatter_k chain (2 launches + cnt traffic gone).
// Blocks [NB_P, ...): GEMM h16 = fp16(x @ W^T), split-bf16 MFMA. Whi/Wlo
//   staged via plain b128 copies. Output fp16 strip-major [2][NN][64].
// ---------------------------------------------------------------------------
__global__ __launch_bounds__(256) void gemm_scatter(
    const float* __restrict__ x, const us8* __restrict__ Whi,
    const us8* __restrict__ Wlo, f16* __restrict__ h16,
    const int* __restrict__ row, const int* __restrict__ col,
    const float* __restrict__ w, int* __restrict__ pcur,
    u64* __restrict__ part) {
    const int t = threadIdx.x;
    __shared__ us8 WH[2048];  // 32 KB hi; reused as bins/off0/cur (scatter)
    __shared__ us8 WL[2048];  // 32 KB lo

    if (blockIdx.x < NB_P) {
        // ---- scatter role ----
        int* bins = (int*)WH;        // [256] (NP used)
        int* off0 = bins + 256;      // [256]
        int* cur  = off0 + 256;      // [256]
        for (int i = t; i < NP; i += 256) { bins[i] = 0; cur[i] = 0; }
        __syncthreads();
        const int e0 = blockIdx.x * EPB + t;
        int cc[8];
#pragma unroll
        for (int s = 0; s < 8; ++s) {
            const int e = e0 + s * 256;
            cc[s] = (e < NE) ? col[e] : -1;
            if (cc[s] >= 0) atomicAdd(&bins[cc[s] >> 8], 1);
        }
        __syncthreads();
        for (int i = t; i < NP; i += 256)
            off0[i] = bins[i] ? atomicAdd(&pcur[i], bins[i]) : 0;
        __syncthreads();
#pragma unroll
        for (int s = 0; s < 8; ++s) {
            const int e = e0 + s * 256;
            if (e < NE) {
                const int c = cc[s];
                const int p = c >> 8;
                const int lr = atomicAdd(&cur[p], 1);
                part[off0[p] + lr] = ((u64)__float_as_uint(w[e]) << 32) |
                                     ((u32)row[e] << 8) | (u32)(c & 255);
            }
        }
        return;
    }

    // ---- GEMM role ----
    const int g = (blockIdx.x - NB_P) * 4 + (t >> 6);
    const int lane = t & 63;
    const int gc = (g < NWAVE) ? g : (NWAVE - 1);
    const int row0 = gc * 16;

    // issue all 8 cold x loads up front (128B/lane, 16 full lines per wave)
    const float* px = x + (size_t)(row0 + (lane & 15)) * D + (lane >> 4) * 8;
    float4 ar[8];
#pragma unroll
    for (int c = 0; c < 4; ++c) {
        ar[2 * c]     = *(const float4*)(px + c * 32);
        ar[2 * c + 1] = *(const float4*)(px + c * 32 + 4);
    }

    // stage pre-converted tables (64KB, plain b128 copies, L2-resident)
#pragma unroll
    for (int i = 0; i < 8; ++i) {
        WH[t + i * 256] = Whi[t + i * 256];
        WL[t + i * 256] = Wlo[t + i * 256];
    }
    __syncthreads();
    if (g >= NWAVE) return;

    f32x4 acc[8];
#pragma unroll
    for (int nt = 0; nt < 8; ++nt) acc[nt] = (f32x4){0.f, 0.f, 0.f, 0.f};

#pragma unroll
    for (int c = 0; c < 4; ++c) {
        float v[8];
        *(float4*)&v[0] = ar[2 * c];
        *(float4*)&v[4] = ar[2 * c + 1];
        us8 hiu, lou;
#pragma unroll
        for (int j = 0; j < 8; ++j) {
            const unsigned short hb = f2bf(v[j]);
            hiu[j] = hb;
            lou[j] = f2bf(v[j] - bf2f(hb));
        }
        const bf16x8 ah = *(const bf16x8*)&hiu;
        const bf16x8 al = *(const bf16x8*)&lou;
#pragma unroll
        for (int nt = 0; nt < 8; ++nt) {
            const bf16x8 bh = *(const bf16x8*)&WH[c * 512 + nt * 64 + lane];
            const bf16x8 bl = *(const bf16x8*)&WL[c * 512 + nt * 64 + lane];
            acc[nt] = __builtin_amdgcn_mfma_f32_16x16x32_bf16(ah, bh, acc[nt], 0, 0, 0);
            acc[nt] = __builtin_amdgcn_mfma_f32_16x16x32_bf16(al, bh, acc[nt], 0, 0, 0);
            acc[nt] = __builtin_amdgcn_mfma_f32_16x16x32_bf16(ah, bl, acc[nt], 0, 0, 0);
        }
    }

    // epilogue: C/D layout col = lane&15, row = (lane>>4)*4 + r (verified).
    // fp16 strip-major [2][NN][64]: strip = nt>>2, col = (nt&3)*16 + cl.
    const int q = lane >> 4, cl = lane & 15;
#pragma unroll
    for (int nt = 0; nt < 8; ++nt) {
        f16* o = h16 + (size_t)(nt >> 2) * ((size_t)NN * 64) + (nt & 3) * 16 + cl;
#pragma unroll
        for (int r = 0; r < 4; ++r)
            o[(size_t)(row0 + q * 4 + r) * 64] = (f16)acc[nt][r];
    }
}

// ---------------------------------------------------------------------------
// per-partition CSR finish (slab coordinates). Block p owns nodes
// [p*256, p*256+256) and slab edges [p*MAXCAP, pcur[p]). LDS count + float
// weighted-degree -> dinv; LDS scan -> base[node] (slab coords) + kcnt[node];
// scatter sedge with PARTIAL norm w*dinv[col] (dinv[row] applied in hops).
__global__ __launch_bounds__(256) void csr_k(
    const u64* __restrict__ part, const int* __restrict__ pcur,
    int* __restrict__ base, int* __restrict__ kcnt,
    float* __restrict__ dinv, int2* __restrict__ sedge) {
    __shared__ u32 cntL[256];
    __shared__ float wsL[256];   // weighted degree, then reused as dinv
    __shared__ int curL[256];
    __shared__ int sw[256];
    const int p = blockIdx.x, tid = threadIdx.x;
    const int eb = p * MAXCAP, ee = pcur[p];

    cntL[tid] = 0u;
    wsL[tid] = 0.f;
    __syncthreads();
    for (int e = eb + tid; e < ee; e += 256) {
        const u64 pk = part[e];
        const int cl = (int)(pk & 255u);
        atomicAdd(&cntL[cl], 1u);
        atomicAdd(&wsL[cl], __uint_as_float((u32)(pk >> 32)));
    }
    __syncthreads();

    const int node = p * 256 + tid;
    const float di = rsqrtf(1.0f + wsL[tid]);  // deg = 1 (self) + sum_in w
    const int myc = (int)cntL[tid];
    sw[tid] = myc;
    __syncthreads();
    for (int off = 1; off < 256; off <<= 1) {
        int tv = (tid >= off) ? sw[tid - off] : 0;
        __syncthreads();
        if (tid >= off) sw[tid] += tv;
        __syncthreads();
    }
    const int excl = sw[tid] - myc;
    if (node < NN) {
        dinv[node] = di;
        base[node] = eb + excl;
        kcnt[node] = myc;
    }
    __syncthreads();
    wsL[tid] = di;
    curL[tid] = excl;
    __syncthreads();

    for (int e = eb + tid; e < ee; e += 256) {
        const u64 pk = part[e];
        const int cl = (int)(pk & 255u);
        const int r = (int)((pk >> 8) & 0xFFFFu);
        const float wv = __uint_as_float((u32)(pk >> 32));
        const int lr = atomicAdd(&curL[cl], 1);
        int2 ed;
        ed.x = r;
        ed.y = __float_as_int(wv * wsL[cl]);  // partial norm: w * dinv[col]
        sedge[eb + lr] = ed;
    }
}

// ---------------------------------------------------------------------------
// one hop: dst[n] = dinv[n]^2 * src[n] + sum_in (w*dinv[r]*dinv[n]) * src[r]
// sedge.y = w*dinv[col]; dinv[row] applied in-loop (L2-resident table).
// fp16 strip-major [2][NN][64]: each gather = exactly one 128B line.
// 8-lane groups (fp16x8); blockIdx.y = strip. unroll 4 (unroll 8 blew the
// 64-VGPR occupancy cliff in round 8, +17 µs). Slab CSR: b = base[node],
// k = kcnt[node].
// OUTF=0: write fp16 strip-major; OUTF=1: write fp32 out.
// ---------------------------------------------------------------------------
template <int OUTF>
__global__ __launch_bounds__(256) void hop_kernel(
    const f16* __restrict__ src, f16* __restrict__ dst16,
    float* __restrict__ dstf, const int2* __restrict__ sedge,
    const int* __restrict__ base, const int* __restrict__ kcnt,
    const float* __restrict__ dinv) {
    const int node = blockIdx.x * 32 + (threadIdx.x >> 3);
    if (node >= NN) return;
    const int strip = blockIdx.y;
    const int lo8 = (threadIdx.x & 7) * 8;
    const f16* hs = src + (size_t)strip * ((size_t)NN * 64) + lo8;

    const int b = base[node];
    const int k = kcnt[node];

    float acc[8] = {0.f, 0.f, 0.f, 0.f, 0.f, 0.f, 0.f, 0.f};
#pragma unroll 4
    for (int j = 0; j < k; ++j) {
        const int2 ed = sedge[b + j];
        const f16x8 hv = *(const f16x8*)(hs + (size_t)ed.x * 64);
        const float nm = __int_as_float(ed.y) * dinv[ed.x];
#pragma unroll
        for (int i = 0; i < 8; ++i) acc[i] = fmaf(nm, (float)hv[i], acc[i]);
    }
    const float di = dinv[node];
    const float d2 = di * di;
    const f16x8 sv = *(const f16x8*)(hs + (size_t)node * 64);
#pragma unroll
    for (int i = 0; i < 8; ++i) acc[i] = fmaf(d2, (float)sv[i], acc[i]);

    if (OUTF) {
        float* o = dstf + (size_t)node * D + strip * 64 + lo8;
        *(float4*)&o[0] = make_float4(acc[0], acc[1], acc[2], acc[3]);
        *(float4*)&o[4] = make_float4(acc[4], acc[5], acc[6], acc[7]);
    } else {
        f16x8 ov;
#pragma unroll
        for (int i = 0; i < 8; ++i) ov[i] = (f16)acc[i];
        *(f16x8*)(dst16 + (size_t)strip * ((size_t)NN * 64) + (size_t)node * 64 + lo8) = ov;
    }
}

// ---------------------------------------------------------------------------
extern "C" void kernel_launch(void* const* d_in, const int* in_sizes, int n_in,
                              void* d_out, int out_size, void* d_ws,
                              size_t ws_size, hipStream_t stream) {
    const float* x  = (const float*)d_in[0];
    const int*   ei = (const int*)d_in[1];  // [2, NE]: row then col
    const float* w  = (const float*)d_in[2];
    const float* W  = (const float*)d_in[3];
    float* out = (float*)d_out;

    const int* row = ei;
    const int* col = ei + NE;

    // workspace carve-up (~31.9 MB)
    f16* h16a = (f16*)d_ws;                          // 2*NN*64 f16 = 12.8MB
    f16* h16b = h16a + (size_t)2 * NN * 64;          // 12.8MB
    u64* part = (u64*)h16b;                          // 5.6MB alias (dead before hop1)
    us8* Whi = (us8*)(h16b + (size_t)2 * NN * 64);   // 32KB
    us8* Wlo = Whi + 2048;                           // 32KB
    int* pcur = (int*)(Wlo + 2048);                  // NP
    int* base = pcur + NP;                           // NN
    int* kcnt = base + NN;                           // NN
    float* dinv = (float*)(kcnt + NN);               // NN
    int2* sedge = (int2*)(dinv + NN);                // NP*MAXCAP int2 = 5.6MB

    wprep<<<8, 256, 0, stream>>>(W, Whi, Wlo, pcur);
    gemm_scatter<<<NB_P + GGEMM, 256, 0, stream>>>(x, Whi, Wlo, h16a, row, col,
                                                   w, pcur, part);
    csr_k<<<NP, 256, 0, stream>>>(part, pcur, base, kcnt, dinv, sedge);

    hop_kernel<0><<<dim3(GS, NSTRIP), 256, 0, stream>>>(h16a, h16b, nullptr,
                                                        sedge, base, kcnt, dinv);
    hop_kernel<1><<<dim3(GS, NSTRIP), 256, 0, stream>>>(h16b, nullptr, out,
                                                        sedge, base, kcnt, dinv);
}

// Round 11
// 91.357 us; speedup vs baseline: 1.3524x; 1.0330x over previous
//
#include <hip/hip_runtime.h>

typedef unsigned long long u64;
typedef unsigned int u32;
typedef _Float16 f16;

#define NN 50000
#define NE 600000
#define D  128
#define NWAVE 3125        // 50000 / 16 rows per GEMM wave-iteration
#define GB 196            // persistent GEMM blocks (4 waves x 4 iters each)
#define GSTRIDE 784       // GB * 4 waves: row-group stride between iters
#define EPB 2048          // edges per scatter block (8 per thread)
#define NB_P 293          // ceil(600000 / 2048)
#define NP 196            // partitions: col >> 8 (256 nodes each)
#define MAXCAP 3584       // slab capacity/partition (mean 3061, sigma 55: 9.5σ)
#define NSTRIP 2          // hop strips: 64 fp16 cols = 128B = one full line
#define GS 1563           // hop blocks per strip: ceil(50000/32)

typedef __attribute__((ext_vector_type(8))) __bf16 bf16x8;
typedef __attribute__((ext_vector_type(8))) unsigned short us8;
typedef __attribute__((ext_vector_type(8))) f16 f16x8;
typedef __attribute__((ext_vector_type(4))) float f32x4;

__device__ __forceinline__ unsigned short f2bf(float f) {
    u32 u = __float_as_uint(f);
    return (unsigned short)((u + 0x7FFFu + ((u >> 16) & 1u)) >> 16);  // RNE
}
__device__ __forceinline__ float bf2f(unsigned short h) {
    return __uint_as_float((u32)h << 16);
}

// ---------------------------------------------------------------------------
// wprep: convert W ONCE into frag-order split-bf16 tables (2048 chunks) AND
// init the 196 partition slab cursors (pcur[p] = p*MAXCAP).
// ---------------------------------------------------------------------------
__global__ __launch_bounds__(256) void wprep(const float* __restrict__ W,
                                             us8* __restrict__ Whi,
                                             us8* __restrict__ Wlo,
                                             int* __restrict__ pcur) {
    const int i = blockIdx.x * 256 + threadIdx.x;
    if (i < NP) pcur[i] = i * MAXCAP;
    if (i < 2048) {
        const int ln = i & 63, nt = (i >> 6) & 7, kc4 = i >> 9;
        const float* p =
            W + (size_t)(nt * 16 + (ln & 15)) * D + kc4 * 32 + (ln >> 4) * 8;
        float v[8];
        *(float4*)&v[0] = *(const float4*)p;
        *(float4*)&v[4] = *(const float4*)(p + 4);
        us8 hi, lo;
#pragma unroll
        for (int j = 0; j < 8; ++j) {
            const unsigned short hb = f2bf(v[j]);
            hi[j] = hb;
            lo[j] = f2bf(v[j] - bf2f(hb));
        }
        Whi[i] = hi;
        Wlo[i] = lo;
    }
}

// ---------------------------------------------------------------------------
// Fused kernel. Blocks [0, NB_P): SCATTER — LDS-count the block's 2048 edges
//   by partition, reserve slab space with ONE device atomicAdd per touched
//   partition (57k total), write packed edges (w|row|colloc u64) into slabs.
// Blocks [NB_P, NB_P+GB): PERSISTENT GEMM h16 = fp16(x @ W^T), split-bf16
//   MFMA. W staged to LDS ONCE per block (was 782 restages -> 196); each
//   wave loops 4 row-groups with next-iter x-loads prefetched so HBM
//   latency hides under MFMA. Output fp16 strip-major [2][NN][64].
// ---------------------------------------------------------------------------
__global__ __launch_bounds__(256) void gemm_scatter(
    const float* __restrict__ x, const us8* __restrict__ Whi,
    const us8* __restrict__ Wlo, f16* __restrict__ h16,
    const int* __restrict__ row, const int* __restrict__ col,
    const float* __restrict__ w, int* __restrict__ pcur,
    u64* __restrict__ part) {
    const int t = threadIdx.x;
    __shared__ us8 WH[2048];  // 32 KB hi; reused as bins/off0/cur (scatter)
    __shared__ us8 WL[2048];  // 32 KB lo

    if (blockIdx.x < NB_P) {
        // ---- scatter role ----
        int* bins = (int*)WH;        // [256] (NP used)
        int* off0 = bins + 256;      // [256]
        int* cur  = off0 + 256;      // [256]
        for (int i = t; i < NP; i += 256) { bins[i] = 0; cur[i] = 0; }
        __syncthreads();
        const int e0 = blockIdx.x * EPB + t;
        int cc[8];
#pragma unroll
        for (int s = 0; s < 8; ++s) {
            const int e = e0 + s * 256;
            cc[s] = (e < NE) ? col[e] : -1;
            if (cc[s] >= 0) atomicAdd(&bins[cc[s] >> 8], 1);
        }
        __syncthreads();
        for (int i = t; i < NP; i += 256)
            off0[i] = bins[i] ? atomicAdd(&pcur[i], bins[i]) : 0;
        __syncthreads();
#pragma unroll
        for (int s = 0; s < 8; ++s) {
            const int e = e0 + s * 256;
            if (e < NE) {
                const int c = cc[s];
                const int p = c >> 8;
                const int lr = atomicAdd(&cur[p], 1);
                part[off0[p] + lr] = ((u64)__float_as_uint(w[e]) << 32) |
                                     ((u32)row[e] << 8) | (u32)(c & 255);
            }
        }
        return;
    }

    // ---- persistent GEMM role ----
    const int wid = (blockIdx.x - NB_P) * 4 + (t >> 6);
    const int lane = t & 63;
    const int l15 = lane & 15, l4 = lane >> 4;

    // issue iter-0 x loads (128B/lane) before staging so they overlap it
    int g = (wid < NWAVE) ? wid : NWAVE - 1;
    const float* px = x + (size_t)(g * 16 + l15) * D + l4 * 8;
    float4 ar[8];
#pragma unroll
    for (int c = 0; c < 4; ++c) {
        ar[2 * c]     = *(const float4*)(px + c * 32);
        ar[2 * c + 1] = *(const float4*)(px + c * 32 + 4);
    }

    // stage pre-converted tables ONCE (64KB, plain b128 copies, L2-resident)
#pragma unroll
    for (int i = 0; i < 8; ++i) {
        WH[t + i * 256] = Whi[t + i * 256];
        WL[t + i * 256] = Wlo[t + i * 256];
    }
    __syncthreads();

#pragma unroll
    for (int l = 0; l < 4; ++l) {
        // prefetch next iteration's x rows (independent of this iter's MFMA)
        float4 an[8];
        int gn = wid + (l + 1) * GSTRIDE;
        if (gn >= NWAVE) gn = NWAVE - 1;
        if (l < 3) {
            const float* pn = x + (size_t)(gn * 16 + l15) * D + l4 * 8;
#pragma unroll
            for (int c = 0; c < 4; ++c) {
                an[2 * c]     = *(const float4*)(pn + c * 32);
                an[2 * c + 1] = *(const float4*)(pn + c * 32 + 4);
            }
        }

        f32x4 acc[8];
#pragma unroll
        for (int nt = 0; nt < 8; ++nt) acc[nt] = (f32x4){0.f, 0.f, 0.f, 0.f};

#pragma unroll
        for (int c = 0; c < 4; ++c) {
            float v[8];
            *(float4*)&v[0] = ar[2 * c];
            *(float4*)&v[4] = ar[2 * c + 1];
            us8 hiu, lou;
#pragma unroll
            for (int j = 0; j < 8; ++j) {
                const unsigned short hb = f2bf(v[j]);
                hiu[j] = hb;
                lou[j] = f2bf(v[j] - bf2f(hb));
            }
            const bf16x8 ah = *(const bf16x8*)&hiu;
            const bf16x8 al = *(const bf16x8*)&lou;
#pragma unroll
            for (int nt = 0; nt < 8; ++nt) {
                const bf16x8 bh = *(const bf16x8*)&WH[c * 512 + nt * 64 + lane];
                const bf16x8 bl = *(const bf16x8*)&WL[c * 512 + nt * 64 + lane];
                acc[nt] = __builtin_amdgcn_mfma_f32_16x16x32_bf16(ah, bh, acc[nt], 0, 0, 0);
                acc[nt] = __builtin_amdgcn_mfma_f32_16x16x32_bf16(al, bh, acc[nt], 0, 0, 0);
                acc[nt] = __builtin_amdgcn_mfma_f32_16x16x32_bf16(ah, bl, acc[nt], 0, 0, 0);
            }
        }

        // epilogue: C/D layout col = lane&15, row = (lane>>4)*4 + r.
        // fp16 strip-major [2][NN][64]: strip = nt>>2, col = (nt&3)*16 + cl.
        const int row0 = g * 16;
#pragma unroll
        for (int nt = 0; nt < 8; ++nt) {
            f16* o = h16 + (size_t)(nt >> 2) * ((size_t)NN * 64) +
                     (nt & 3) * 16 + l15;
#pragma unroll
            for (int r = 0; r < 4; ++r)
                o[(size_t)(row0 + l4 * 4 + r) * 64] = (f16)acc[nt][r];
        }

        g = gn;
#pragma unroll
        for (int i = 0; i < 8; ++i) ar[i] = an[i];
    }
}

// ---------------------------------------------------------------------------
// per-partition CSR finish (slab coordinates). Block p owns nodes
// [p*256, p*256+256) and slab edges [p*MAXCAP, pcur[p]). LDS count + float
// weighted-degree -> dinv; LDS scan -> base[node] (slab coords) + kcnt[node];
// scatter sedge with PARTIAL norm w*dinv[col] (dinv[row] applied in hops).
__global__ __launch_bounds__(256) void csr_k(
    const u64* __restrict__ part, const int* __restrict__ pcur,
    int* __restrict__ base, int* __restrict__ kcnt,
    float* __restrict__ dinv, int2* __restrict__ sedge) {
    __shared__ u32 cntL[256];
    __shared__ float wsL[256];   // weighted degree, then reused as dinv
    __shared__ int curL[256];
    __shared__ int sw[256];
    const int p = blockIdx.x, tid = threadIdx.x;
    const int eb = p * MAXCAP, ee = pcur[p];

    cntL[tid] = 0u;
    wsL[tid] = 0.f;
    __syncthreads();
    for (int e = eb + tid; e < ee; e += 256) {
        const u64 pk = part[e];
        const int cl = (int)(pk & 255u);
        atomicAdd(&cntL[cl], 1u);
        atomicAdd(&wsL[cl], __uint_as_float((u32)(pk >> 32)));
    }
    __syncthreads();

    const int node = p * 256 + tid;
    const float di = rsqrtf(1.0f + wsL[tid]);  // deg = 1 (self) + sum_in w
    const int myc = (int)cntL[tid];
    sw[tid] = myc;
    __syncthreads();
    for (int off = 1; off < 256; off <<= 1) {
        int tv = (tid >= off) ? sw[tid - off] : 0;
        __syncthreads();
        if (tid >= off) sw[tid] += tv;
        __syncthreads();
    }
    const int excl = sw[tid] - myc;
    if (node < NN) {
        dinv[node] = di;
        base[node] = eb + excl;
        kcnt[node] = myc;
    }
    __syncthreads();
    wsL[tid] = di;
    curL[tid] = excl;
    __syncthreads();

    for (int e = eb + tid; e < ee; e += 256) {
        const u64 pk = part[e];
        const int cl = (int)(pk & 255u);
        const int r = (int)((pk >> 8) & 0xFFFFu);
        const float wv = __uint_as_float((u32)(pk >> 32));
        const int lr = atomicAdd(&curL[cl], 1);
        int2 ed;
        ed.x = r;
        ed.y = __float_as_int(wv * wsL[cl]);  // partial norm: w * dinv[col]
        sedge[eb + lr] = ed;
    }
}

// ---------------------------------------------------------------------------
// one hop: dst[n] = dinv[n]^2 * src[n] + sum_in (w*dinv[r]*dinv[n]) * src[r]
// sedge.y = w*dinv[col]; dinv[row] applied in-loop (L2-resident table).
// fp16 strip-major [2][NN][64]: each gather = exactly one 128B line.
// 8-lane groups (fp16x8); blockIdx.y = strip. unroll 4 (unroll 8 blew the
// 64-VGPR occupancy cliff in round 8, +17 µs). Slab CSR: b = base[node],
// k = kcnt[node].
// OUTF=0: write fp16 strip-major; OUTF=1: write fp32 out.
// ---------------------------------------------------------------------------
template <int OUTF>
__global__ __launch_bounds__(256) void hop_kernel(
    const f16* __restrict__ src, f16* __restrict__ dst16,
    float* __restrict__ dstf, const int2* __restrict__ sedge,
    const int* __restrict__ base, const int* __restrict__ kcnt,
    const float* __restrict__ dinv) {
    const int node = blockIdx.x * 32 + (threadIdx.x >> 3);
    if (node >= NN) return;
    const int strip = blockIdx.y;
    const int lo8 = (threadIdx.x & 7) * 8;
    const f16* hs = src + (size_t)strip * ((size_t)NN * 64) + lo8;

    const int b = base[node];
    const int k = kcnt[node];

    float acc[8] = {0.f, 0.f, 0.f, 0.f, 0.f, 0.f, 0.f, 0.f};
#pragma unroll 4
    for (int j = 0; j < k; ++j) {
        const int2 ed = sedge[b + j];
        const f16x8 hv = *(const f16x8*)(hs + (size_t)ed.x * 64);
        const float nm = __int_as_float(ed.y) * dinv[ed.x];
#pragma unroll
        for (int i = 0; i < 8; ++i) acc[i] = fmaf(nm, (float)hv[i], acc[i]);
    }
    const float di = dinv[node];
    const float d2 = di * di;
    const f16x8 sv = *(const f16x8*)(hs + (size_t)node * 64);
#pragma unroll
    for (int i = 0; i < 8; ++i) acc[i] = fmaf(d2, (float)sv[i], acc[i]);

    if (OUTF) {
        float* o = dstf + (size_t)node * D + strip * 64 + lo8;
        *(float4*)&o[0] = make_float4(acc[0], acc[1], acc[2], acc[3]);
        *(float4*)&o[4] = make_float4(acc[4], acc[5], acc[6], acc[7]);
    } else {
        f16x8 ov;
#pragma unroll
        for (int i = 0; i < 8; ++i) ov[i] = (f16)acc[i];
        *(f16x8*)(dst16 + (size_t)strip * ((size_t)NN * 64) + (size_t)node * 64 + lo8) = ov;
    }
}

// ---------------------------------------------------------------------------
extern "C" void kernel_launch(void* const* d_in, const int* in_sizes, int n_in,
                              void* d_out, int out_size, void* d_ws,
                              size_t ws_size, hipStream_t stream) {
    const float* x  = (const float*)d_in[0];
    const int*   ei = (const int*)d_in[1];  // [2, NE]: row then col
    const float* w  = (const float*)d_in[2];
    const float* W  = (const float*)d_in[3];
    float* out = (float*)d_out;

    const int* row = ei;
    const int* col = ei + NE;

    // workspace carve-up (~31.9 MB)
    f16* h16a = (f16*)d_ws;                          // 2*NN*64 f16 = 12.8MB
    f16* h16b = h16a + (size_t)2 * NN * 64;          // 12.8MB
    u64* part = (u64*)h16b;                          // 5.6MB alias (dead before hop1)
    us8* Whi = (us8*)(h16b + (size_t)2 * NN * 64);   // 32KB
    us8* Wlo = Whi + 2048;                           // 32KB
    int* pcur = (int*)(Wlo + 2048);                  // NP
    int* base = pcur + NP;                           // NN
    int* kcnt = base + NN;                           // NN
    float* dinv = (float*)(kcnt + NN);               // NN
    int2* sedge = (int2*)(dinv + NN);                // NP*MAXCAP int2 = 5.6MB

    wprep<<<8, 256, 0, stream>>>(W, Whi, Wlo, pcur);
    gemm_scatter<<<NB_P + GB, 256, 0, stream>>>(x, Whi, Wlo, h16a, row, col,
                                                w, pcur, part);
    csr_k<<<NP, 256, 0, stream>>>(part, pcur, base, kcnt, dinv, sedge);

    hop_kernel<0><<<dim3(GS, NSTRIP), 256, 0, stream>>>(h16a, h16b, nullptr,
                                                        sedge, base, kcnt, dinv);
    hop_kernel<1><<<dim3(GS, NSTRIP), 256, 0, stream>>>(h16b, nullptr, out,
                                                        sedge, base, kcnt, dinv);
}

// Round 12
// 91.073 us; speedup vs baseline: 1.3567x; 1.0031x over previous
//
#include <hip/hip_runtime.h>

typedef unsigned long long u64;
typedef unsigned int u32;
typedef _Float16 f16;

#define NN 50000
#define NE 600000
#define D  128
#define NWAVE 3125        // 50000 / 16 rows per GEMM wave-iteration
#define GB 196            // persistent GEMM blocks (4 waves x 4 iters each)
#define GSTRIDE 784       // GB * 4 waves: row-group stride between iters
#define EPB 2048          // edges per scatter block (8 per thread)
#define NB_P 293          // ceil(600000 / 2048)
#define NP 196            // partitions: col >> 8 (256 nodes each)
#define MAXCAP 3584       // slab capacity/partition (mean 3061, sigma 55: 9.5σ)
#define NSTRIP 2          // hop strips: 64 fp16 cols = 128B = one full line
#define GS 1563           // hop blocks per strip: ceil(50000/32)

typedef __attribute__((ext_vector_type(8))) __bf16 bf16x8;
typedef __attribute__((ext_vector_type(8))) unsigned short us8;
typedef __attribute__((ext_vector_type(8))) f16 f16x8;
typedef __attribute__((ext_vector_type(4))) float f32x4;

__device__ __forceinline__ unsigned short f2bf(float f) {
    u32 u = __float_as_uint(f);
    return (unsigned short)((u + 0x7FFFu + ((u >> 16) & 1u)) >> 16);  // RNE
}
__device__ __forceinline__ float bf2f(unsigned short h) {
    return __uint_as_float((u32)h << 16);
}

// ---------------------------------------------------------------------------
// wprep: convert W ONCE into frag-order split-bf16 tables (2048 chunks) AND
// init the 196 partition slab cursors (pcur[p] = p*MAXCAP).
// ---------------------------------------------------------------------------
__global__ __launch_bounds__(256) void wprep(const float* __restrict__ W,
                                             us8* __restrict__ Whi,
                                             us8* __restrict__ Wlo,
                                             int* __restrict__ pcur) {
    const int i = blockIdx.x * 256 + threadIdx.x;
    if (i < NP) pcur[i] = i * MAXCAP;
    if (i < 2048) {
        const int ln = i & 63, nt = (i >> 6) & 7, kc4 = i >> 9;
        const float* p =
            W + (size_t)(nt * 16 + (ln & 15)) * D + kc4 * 32 + (ln >> 4) * 8;
        float v[8];
        *(float4*)&v[0] = *(const float4*)p;
        *(float4*)&v[4] = *(const float4*)(p + 4);
        us8 hi, lo;
#pragma unroll
        for (int j = 0; j < 8; ++j) {
            const unsigned short hb = f2bf(v[j]);
            hi[j] = hb;
            lo[j] = f2bf(v[j] - bf2f(hb));
        }
        Whi[i] = hi;
        Wlo[i] = lo;
    }
}

// ---------------------------------------------------------------------------
// Fused kernel. Blocks [0, NB_P): SCATTER — LDS-count the block's 2048 edges
//   by partition, reserve slab space with ONE device atomicAdd per touched
//   partition (57k total), write packed edges (w|row|colloc u64) into slabs.
// Blocks [NB_P, NB_P+GB): PERSISTENT GEMM h16 = fp16(x @ W^T), split-bf16
//   MFMA. W staged to LDS ONCE per block; each wave loops 4 row-groups with
//   next-iter x-loads prefetched. Output fp16 strip-major [2][NN][64].
// ---------------------------------------------------------------------------
__global__ __launch_bounds__(256) void gemm_scatter(
    const float* __restrict__ x, const us8* __restrict__ Whi,
    const us8* __restrict__ Wlo, f16* __restrict__ h16,
    const int* __restrict__ row, const int* __restrict__ col,
    const float* __restrict__ w, int* __restrict__ pcur,
    u64* __restrict__ part) {
    const int t = threadIdx.x;
    __shared__ us8 WH[2048];  // 32 KB hi; reused as bins/off0/cur (scatter)
    __shared__ us8 WL[2048];  // 32 KB lo

    if (blockIdx.x < NB_P) {
        // ---- scatter role ----
        int* bins = (int*)WH;        // [256] (NP used)
        int* off0 = bins + 256;      // [256]
        int* cur  = off0 + 256;      // [256]
        for (int i = t; i < NP; i += 256) { bins[i] = 0; cur[i] = 0; }
        __syncthreads();
        const int e0 = blockIdx.x * EPB + t;
        int cc[8];
#pragma unroll
        for (int s = 0; s < 8; ++s) {
            const int e = e0 + s * 256;
            cc[s] = (e < NE) ? col[e] : -1;
            if (cc[s] >= 0) atomicAdd(&bins[cc[s] >> 8], 1);
        }
        __syncthreads();
        for (int i = t; i < NP; i += 256)
            off0[i] = bins[i] ? atomicAdd(&pcur[i], bins[i]) : 0;
        __syncthreads();
#pragma unroll
        for (int s = 0; s < 8; ++s) {
            const int e = e0 + s * 256;
            if (e < NE) {
                const int c = cc[s];
                const int p = c >> 8;
                const int lr = atomicAdd(&cur[p], 1);
                part[off0[p] + lr] = ((u64)__float_as_uint(w[e]) << 32) |
                                     ((u32)row[e] << 8) | (u32)(c & 255);
            }
        }
        return;
    }

    // ---- persistent GEMM role ----
    const int wid = (blockIdx.x - NB_P) * 4 + (t >> 6);
    const int lane = t & 63;
    const int l15 = lane & 15, l4 = lane >> 4;

    // issue iter-0 x loads (128B/lane) before staging so they overlap it
    int g = (wid < NWAVE) ? wid : NWAVE - 1;
    const float* px = x + (size_t)(g * 16 + l15) * D + l4 * 8;
    float4 ar[8];
#pragma unroll
    for (int c = 0; c < 4; ++c) {
        ar[2 * c]     = *(const float4*)(px + c * 32);
        ar[2 * c + 1] = *(const float4*)(px + c * 32 + 4);
    }

    // stage pre-converted tables ONCE (64KB, plain b128 copies, L2-resident)
#pragma unroll
    for (int i = 0; i < 8; ++i) {
        WH[t + i * 256] = Whi[t + i * 256];
        WL[t + i * 256] = Wlo[t + i * 256];
    }
    __syncthreads();

#pragma unroll
    for (int l = 0; l < 4; ++l) {
        // prefetch next iteration's x rows (independent of this iter's MFMA)
        float4 an[8];
        int gn = wid + (l + 1) * GSTRIDE;
        if (gn >= NWAVE) gn = NWAVE - 1;
        if (l < 3) {
            const float* pn = x + (size_t)(gn * 16 + l15) * D + l4 * 8;
#pragma unroll
            for (int c = 0; c < 4; ++c) {
                an[2 * c]     = *(const float4*)(pn + c * 32);
                an[2 * c + 1] = *(const float4*)(pn + c * 32 + 4);
            }
        }

        f32x4 acc[8];
#pragma unroll
        for (int nt = 0; nt < 8; ++nt) acc[nt] = (f32x4){0.f, 0.f, 0.f, 0.f};

#pragma unroll
        for (int c = 0; c < 4; ++c) {
            float v[8];
            *(float4*)&v[0] = ar[2 * c];
            *(float4*)&v[4] = ar[2 * c + 1];
            us8 hiu, lou;
#pragma unroll
            for (int j = 0; j < 8; ++j) {
                const unsigned short hb = f2bf(v[j]);
                hiu[j] = hb;
                lou[j] = f2bf(v[j] - bf2f(hb));
            }
            const bf16x8 ah = *(const bf16x8*)&hiu;
            const bf16x8 al = *(const bf16x8*)&lou;
#pragma unroll
            for (int nt = 0; nt < 8; ++nt) {
                const bf16x8 bh = *(const bf16x8*)&WH[c * 512 + nt * 64 + lane];
                const bf16x8 bl = *(const bf16x8*)&WL[c * 512 + nt * 64 + lane];
                acc[nt] = __builtin_amdgcn_mfma_f32_16x16x32_bf16(ah, bh, acc[nt], 0, 0, 0);
                acc[nt] = __builtin_amdgcn_mfma_f32_16x16x32_bf16(al, bh, acc[nt], 0, 0, 0);
                acc[nt] = __builtin_amdgcn_mfma_f32_16x16x32_bf16(ah, bl, acc[nt], 0, 0, 0);
            }
        }

        // epilogue: C/D layout col = lane&15, row = (lane>>4)*4 + r.
        // fp16 strip-major [2][NN][64]: strip = nt>>2, col = (nt&3)*16 + cl.
        const int row0 = g * 16;
#pragma unroll
        for (int nt = 0; nt < 8; ++nt) {
            f16* o = h16 + (size_t)(nt >> 2) * ((size_t)NN * 64) +
                     (nt & 3) * 16 + l15;
#pragma unroll
            for (int r = 0; r < 4; ++r)
                o[(size_t)(row0 + l4 * 4 + r) * 64] = (f16)acc[nt][r];
        }

        g = gn;
#pragma unroll
        for (int i = 0; i < 8; ++i) ar[i] = an[i];
    }
}

// ---------------------------------------------------------------------------
// per-partition CSR finish (slab coordinates). Block p owns nodes
// [p*256, p*256+256) and slab edges [p*MAXCAP, pcur[p]). LDS count + float
// weighted-degree -> dinv; LDS scan -> base[node] + kcnt[node]; scatter
// sedge with PARTIAL norm w*dinv[col].
// NEW: each node's edge list is ordered by SOURCE-QUARTER (boundaries
// 12500/25000/37500). The hop's j-loop then walks sources in ~1.6MB/strip
// phases that fit an XCD L2 (footprint was 6.4MB, ~50% hit) — raising hop
// L2 hit rate with ZERO change to the hop kernel or any data volume.
__global__ __launch_bounds__(256) void csr_k(
    const u64* __restrict__ part, const int* __restrict__ pcur,
    int* __restrict__ base, int* __restrict__ kcnt,
    float* __restrict__ dinv, int2* __restrict__ sedge) {
    __shared__ u32 cntQ[4][256];   // per-(quarter, node) counts
    __shared__ int curQ[4][256];   // per-(quarter, node) cursors
    __shared__ float wsL[256];     // weighted degree, then reused as dinv
    __shared__ int sw[256];
    const int p = blockIdx.x, tid = threadIdx.x;
    const int eb = p * MAXCAP, ee = pcur[p];

#pragma unroll
    for (int q = 0; q < 4; ++q) cntQ[q][tid] = 0u;
    wsL[tid] = 0.f;
    __syncthreads();
    for (int e = eb + tid; e < ee; e += 256) {
        const u64 pk = part[e];
        const int cl = (int)(pk & 255u);
        const int r = (int)((pk >> 8) & 0xFFFFu);
        const int q = (r >= 37500) ? 3 : (r >= 25000) ? 2 : (r >= 12500) ? 1 : 0;
        atomicAdd(&cntQ[q][cl], 1u);
        atomicAdd(&wsL[cl], __uint_as_float((u32)(pk >> 32)));
    }
    __syncthreads();

    const int node = p * 256 + tid;
    const float di = rsqrtf(1.0f + wsL[tid]);  // deg = 1 (self) + sum_in w
    const int c0 = (int)cntQ[0][tid], c1 = (int)cntQ[1][tid];
    const int c2 = (int)cntQ[2][tid], c3 = (int)cntQ[3][tid];
    const int myc = c0 + c1 + c2 + c3;
    sw[tid] = myc;
    __syncthreads();
    for (int off = 1; off < 256; off <<= 1) {
        int tv = (tid >= off) ? sw[tid - off] : 0;
        __syncthreads();
        if (tid >= off) sw[tid] += tv;
        __syncthreads();
    }
    const int excl = sw[tid] - myc;
    if (node < NN) {
        dinv[node] = di;
        base[node] = eb + excl;
        kcnt[node] = myc;
    }
    __syncthreads();
    wsL[tid] = di;
    curQ[0][tid] = excl;
    curQ[1][tid] = excl + c0;
    curQ[2][tid] = excl + c0 + c1;
    curQ[3][tid] = excl + c0 + c1 + c2;
    __syncthreads();

    for (int e = eb + tid; e < ee; e += 256) {
        const u64 pk = part[e];
        const int cl = (int)(pk & 255u);
        const int r = (int)((pk >> 8) & 0xFFFFu);
        const int q = (r >= 37500) ? 3 : (r >= 25000) ? 2 : (r >= 12500) ? 1 : 0;
        const float wv = __uint_as_float((u32)(pk >> 32));
        const int lr = atomicAdd(&curQ[q][cl], 1);
        int2 ed;
        ed.x = r;
        ed.y = __float_as_int(wv * wsL[cl]);  // partial norm: w * dinv[col]
        sedge[eb + lr] = ed;
    }
}

// ---------------------------------------------------------------------------
// one hop: dst[n] = dinv[n]^2 * src[n] + sum_in (w*dinv[r]*dinv[n]) * src[r]
// sedge.y = w*dinv[col]; dinv[row] applied in-loop (L2-resident table).
// fp16 strip-major [2][NN][64]: each gather = exactly one 128B line.
// 8-lane groups (fp16x8); blockIdx.y = strip. unroll 4 (unroll 8 blew the
// 64-VGPR occupancy cliff in round 8, +17 µs). Edge lists are source-
// quarter-ordered by csr_k -> gathers sweep L2-sized source phases.
// OUTF=0: write fp16 strip-major; OUTF=1: write fp32 out.
// ---------------------------------------------------------------------------
template <int OUTF>
__global__ __launch_bounds__(256) void hop_kernel(
    const f16* __restrict__ src, f16* __restrict__ dst16,
    float* __restrict__ dstf, const int2* __restrict__ sedge,
    const int* __restrict__ base, const int* __restrict__ kcnt,
    const float* __restrict__ dinv) {
    const int node = blockIdx.x * 32 + (threadIdx.x >> 3);
    if (node >= NN) return;
    const int strip = blockIdx.y;
    const int lo8 = (threadIdx.x & 7) * 8;
    const f16* hs = src + (size_t)strip * ((size_t)NN * 64) + lo8;

    const int b = base[node];
    const int k = kcnt[node];

    float acc[8] = {0.f, 0.f, 0.f, 0.f, 0.f, 0.f, 0.f, 0.f};
#pragma unroll 4
    for (int j = 0; j < k; ++j) {
        const int2 ed = sedge[b + j];
        const f16x8 hv = *(const f16x8*)(hs + (size_t)ed.x * 64);
        const float nm = __int_as_float(ed.y) * dinv[ed.x];
#pragma unroll
        for (int i = 0; i < 8; ++i) acc[i] = fmaf(nm, (float)hv[i], acc[i]);
    }
    const float di = dinv[node];
    const float d2 = di * di;
    const f16x8 sv = *(const f16x8*)(hs + (size_t)node * 64);
#pragma unroll
    for (int i = 0; i < 8; ++i) acc[i] = fmaf(d2, (float)sv[i], acc[i]);

    if (OUTF) {
        float* o = dstf + (size_t)node * D + strip * 64 + lo8;
        *(float4*)&o[0] = make_float4(acc[0], acc[1], acc[2], acc[3]);
        *(float4*)&o[4] = make_float4(acc[4], acc[5], acc[6], acc[7]);
    } else {
        f16x8 ov;
#pragma unroll
        for (int i = 0; i < 8; ++i) ov[i] = (f16)acc[i];
        *(f16x8*)(dst16 + (size_t)strip * ((size_t)NN * 64) + (size_t)node * 64 + lo8) = ov;
    }
}

// ---------------------------------------------------------------------------
extern "C" void kernel_launch(void* const* d_in, const int* in_sizes, int n_in,
                              void* d_out, int out_size, void* d_ws,
                              size_t ws_size, hipStream_t stream) {
    const float* x  = (const float*)d_in[0];
    const int*   ei = (const int*)d_in[1];  // [2, NE]: row then col
    const float* w  = (const float*)d_in[2];
    const float* W  = (const float*)d_in[3];
    float* out = (float*)d_out;

    const int* row = ei;
    const int* col = ei + NE;

    // workspace carve-up (~31.9 MB)
    f16* h16a = (f16*)d_ws;                          // 2*NN*64 f16 = 12.8MB
    f16* h16b = h16a + (size_t)2 * NN * 64;          // 12.8MB
    u64* part = (u64*)h16b;                          // 5.6MB alias (dead before hop1)
    us8* Whi = (us8*)(h16b + (size_t)2 * NN * 64);   // 32KB
    us8* Wlo = Whi + 2048;                           // 32KB
    int* pcur = (int*)(Wlo + 2048);                  // NP
    int* base = pcur + NP;                           // NN
    int* kcnt = base + NN;                           // NN
    float* dinv = (float*)(kcnt + NN);               // NN
    int2* sedge = (int2*)(dinv + NN);                // NP*MAXCAP int2 = 5.6MB

    wprep<<<8, 256, 0, stream>>>(W, Whi, Wlo, pcur);
    gemm_scatter<<<NB_P + GB, 256, 0, stream>>>(x, Whi, Wlo, h16a, row, col,
                                                w, pcur, part);
    csr_k<<<NP, 256, 0, stream>>>(part, pcur, base, kcnt, dinv, sedge);

    hop_kernel<0><<<dim3(GS, NSTRIP), 256, 0, stream>>>(h16a, h16b, nullptr,
                                                        sedge, base, kcnt, dinv);
    hop_kernel<1><<<dim3(GS, NSTRIP), 256, 0, stream>>>(h16b, nullptr, out,
                                                        sedge, base, kcnt, dinv);
}